// Round 12
// baseline (291.988 us; speedup 1.0000x reference)
//
#include <hip/hip_runtime.h>

#define NT 1024      // N_TOPICS
#define TD 128       // TOPIC_DIM
#define HID 512      // HIDDEN
#define NH 8         // N_HEADS
#define HD 64        // HEAD_DIM
#define NB 8         // BATCH

typedef unsigned short us;
typedef short bf16x8 __attribute__((ext_vector_type(8)));
typedef float f32x4 __attribute__((ext_vector_type(4)));

#define LOG2E 1.44269504f

__device__ __forceinline__ us f2bf(float x) {
    unsigned int u = __float_as_uint(x);
    return (us)((u + 0x7FFFu + ((u >> 16) & 1u)) >> 16);
}
__device__ __forceinline__ float bf2f(us s) {
    return __uint_as_float(((unsigned int)s) << 16);
}

// ==== kprep: kmax (0-1023) | node0 MFMA (1024-1151) | gW transpose (1152-1279) | ws2 (1280-1287)
__global__ __launch_bounds__(256) void kprep(const float* __restrict__ tm, float* __restrict__ part,
                                             const float* __restrict__ emb, const float* __restrict__ sW,
                                             const float* __restrict__ sb, us* __restrict__ node0b,
                                             const float* __restrict__ gW, us* __restrict__ Wt,
                                             const float* __restrict__ ga, float* __restrict__ ws2,
                                             const float* __restrict__ fc2b, float* __restrict__ out) {
    __shared__ __align__(16) float smf[8768];   // 35 KB shared by branches
    int bx = blockIdx.x, t = threadIdx.x;
    if (bx < 1024) {
        const float4* tm4 = (const float4*)tm;
        size_t base = (size_t)bx * 256 + t;
        float m = -1e30f;
        #pragma unroll
        for (int k = 0; k < 8; k++) {
            float4 v = tm4[base + (size_t)k * 262144];
            m = fmaxf(m, fmaxf(fmaxf(v.x, v.y), fmaxf(v.z, v.w)));
        }
        smf[t] = m; __syncthreads();
        for (int s = 128; s > 0; s >>= 1) { if (t < s) smf[t] = fmaxf(smf[t], smf[t + s]); __syncthreads(); }
        if (t == 0) part[bx] = smf[0];
    } else if (bx < 1152) {
        // node0 = emb @ sW^T + sb via MFMA. block: (iblk 16) x (oseg 8); K=128, one barrier.
        int g = bx - 1024; int iblk = g & 15, oseg = g >> 4;
        us* As = (us*)smf;              // [64][136]
        us* Bs = (us*)smf + 64 * 136;   // [64][136]
        const float4* esrc = (const float4*)(emb + (size_t)iblk * 64 * TD);
        const float4* wsrc = (const float4*)(sW + (size_t)oseg * 64 * TD);
        #pragma unroll
        for (int rep = 0; rep < 8; rep++) {
            int f = rep * 256 + t;
            int row = f >> 5, c4 = f & 31;
            float4 av = esrc[f];
            float4 bv = wsrc[f];
            us pa[4] = {f2bf(av.x), f2bf(av.y), f2bf(av.z), f2bf(av.w)};
            us pb[4] = {f2bf(bv.x), f2bf(bv.y), f2bf(bv.z), f2bf(bv.w)};
            *(uint2*)&As[row * 136 + c4 * 4] = *(uint2*)pa;
            *(uint2*)&Bs[row * 136 + c4 * 4] = *(uint2*)pb;
        }
        __syncthreads();
        int l = t & 63, w = t >> 6, m = l & 15, q = l >> 4;
        f32x4 acc[4];
        #pragma unroll
        for (int ot = 0; ot < 4; ot++) acc[ot] = (f32x4){0.f, 0.f, 0.f, 0.f};
        #pragma unroll
        for (int ks = 0; ks < 4; ks++) {
            bf16x8 a = *(const bf16x8*)&As[(w * 16 + m) * 136 + ks * 32 + q * 8];
            #pragma unroll
            for (int ot = 0; ot < 4; ot++) {
                bf16x8 b = *(const bf16x8*)&Bs[(ot * 16 + m) * 136 + ks * 32 + q * 8];
                acc[ot] = __builtin_amdgcn_mfma_f32_16x16x32_bf16(a, b, acc[ot], 0, 0, 0);
            }
        }
        #pragma unroll
        for (int ot = 0; ot < 4; ot++) {
            int col = oseg * 64 + ot * 16 + m;
            float sbv = sb[col];
            #pragma unroll
            for (int rr = 0; rr < 4; rr++) {
                int rowi = iblk * 64 + w * 16 + q * 4 + rr;
                node0b[(size_t)rowi * HID + col] = f2bf(acc[ot][rr] + sbv);
            }
        }
    } else if (bx < 1280) {
        // Wt[lh][o][k] = bf16(gW[lh][k][o]) via LDS tile transpose
        int g = bx - 1152; int lh = g >> 3, kt = g & 7;
        float* tile = smf;   // [64][65]
        const float4* src = (const float4*)(gW + ((size_t)lh * HID + kt * 64) * HD);
        #pragma unroll
        for (int rep = 0; rep < 4; rep++) {
            int f = rep * 256 + t;
            float4 v = src[f];
            int row = f >> 4, col = (f & 15) * 4;
            float* d = tile + row * 65 + col;
            d[0] = v.x; d[1] = v.y; d[2] = v.z; d[3] = v.w;
        }
        __syncthreads();
        int o = t >> 2, ks = (t & 3) * 16;
        us pk[16];
        #pragma unroll
        for (int j = 0; j < 16; j++) pk[j] = f2bf(tile[(ks + j) * 65 + o]);
        us* dst = Wt + (size_t)lh * HD * HID + (size_t)o * HID + kt * 64 + ks;
        *(uint4*)dst = *(uint4*)pk;
        *(uint4*)(dst + 8) = *(uint4*)&pk[8];
    } else {
        // ws2[h'][k] = sum_o gW2[h'][k][o]*a2src[o]; ws2[8+h'][k] = ... a2dst[o]
        int hp = bx - 1280;   // 0..7
        if (hp == 0 && t < NB) out[t] = fc2b[0];   // init for khead2 atomics
        const float* gsrc = ga + (size_t)(NH + hp) * 2 * HD;
        const float* wbase = gW + (size_t)(NH + hp) * HID * HD;
        #pragma unroll
        for (int rep = 0; rep < 2; rep++) {
            int k = rep * 256 + t;
            const float* wr = wbase + (size_t)k * HD;
            float s = 0.f, d = 0.f;
            #pragma unroll 8
            for (int o = 0; o < HD; o++) {
                float wv = wr[o];
                s = fmaf(wv, gsrc[o], s);
                d = fmaf(wv, gsrc[HD + o], d);
            }
            ws2[hp * HID + k] = s;
            ws2[(8 + hp) * HID + k] = d;
        }
    }
}

// ============ LDS-free layer-1 GEMM body: direct-fragment global loads, no barriers =====
__device__ __forceinline__ void gemm1_body(const us* __restrict__ A, const us* __restrict__ W,
                                           const float* __restrict__ gav, us* __restrict__ outT,
                                           float* __restrict__ esO, float* __restrict__ edO,
                                           int iblk, int h, int t) {
    int l = t & 63, w = t >> 6, m = l & 15, q = l >> 4;
    const us* ar = A + ((size_t)(iblk * 64 + w * 16 + m)) * HID + q * 8;
    const us* br = W + ((size_t)(h * HD) + m) * HID + q * 8;
    f32x4 acc[4];
    #pragma unroll
    for (int ot = 0; ot < 4; ot++) acc[ot] = (f32x4){0.f, 0.f, 0.f, 0.f};
    #pragma unroll 4
    for (int k0 = 0; k0 < HID; k0 += 32) {
        bf16x8 a = *(const bf16x8*)(ar + k0);
        acc[0] = __builtin_amdgcn_mfma_f32_16x16x32_bf16(a, *(const bf16x8*)(br + k0), acc[0], 0, 0, 0);
        acc[1] = __builtin_amdgcn_mfma_f32_16x16x32_bf16(a, *(const bf16x8*)(br + 16 * HID + k0), acc[1], 0, 0, 0);
        acc[2] = __builtin_amdgcn_mfma_f32_16x16x32_bf16(a, *(const bf16x8*)(br + 32 * HID + k0), acc[2], 0, 0, 0);
        acc[3] = __builtin_amdgcn_mfma_f32_16x16x32_bf16(a, *(const bf16x8*)(br + 48 * HID + k0), acc[3], 0, 0, 0);
    }
    const float* gas = gav + h * 2 * HD;
    float gs[4], gd[4];
    #pragma unroll
    for (int ot = 0; ot < 4; ot++) { gs[ot] = gas[ot * 16 + m]; gd[ot] = gas[HD + ot * 16 + m]; }
    #pragma unroll
    for (int rr = 0; rr < 4; rr++) {
        float s = 0.f, d = 0.f;
        #pragma unroll
        for (int ot = 0; ot < 4; ot++) { float v = acc[ot][rr]; s = fmaf(v, gs[ot], s); d = fmaf(v, gd[ot], d); }
        #pragma unroll
        for (int mask = 1; mask < 16; mask <<= 1) { s += __shfl_xor(s, mask); d += __shfl_xor(d, mask); }
        if (m == 0) {
            int rowi = iblk * 64 + w * 16 + q * 4 + rr;
            esO[h * NT + rowi] = s;
            edO[h * NT + rowi] = d;
        }
    }
    #pragma unroll
    for (int ot = 0; ot < 4; ot++) {
        int col = h * HD + ot * 16 + m;
        #pragma unroll
        for (int rr = 0; rr < 4; rr++) {
            int i_loc = iblk * 64 + w * 16 + q * 4 + rr;
            outT[(size_t)col * NT + i_loc] = f2bf(acc[ot][rr]);
        }
    }
}

// ==== kphase1: ktw (0-2047) | layer-1 GEMM (2048-2175) | zero es2q/pv/pl (2176-2180) ====
#define ZF4 1056   // (64+4096+64)/4 float4s to zero
__global__ __launch_bounds__(256) void kphase1(const float* __restrict__ tm, const int* __restrict__ adj,
                                               const float* __restrict__ part, us* __restrict__ TWb,
                                               const us* __restrict__ node0b, const us* __restrict__ Wt,
                                               const float* __restrict__ ga, us* __restrict__ Ht1,
                                               float* __restrict__ es1, float* __restrict__ ed1,
                                               float* __restrict__ zbase) {
    int bx = blockIdx.x, t = threadIdx.x;
    if (bx < 2048) {
        __shared__ float red[256];
        float m = fmaxf(fmaxf(part[t * 4], part[t * 4 + 1]), fmaxf(part[t * 4 + 2], part[t * 4 + 3]));
        red[t] = m; __syncthreads();
        for (int s = 128; s > 0; s >>= 1) { if (t < s) red[t] = fmaxf(red[t], red[t + s]); __syncthreads(); }
        float tmx = red[0];
        const float C = 0.1f * LOG2E;
        #pragma unroll
        for (int it = 0; it < 4; it++) {
            size_t idx = (((size_t)bx * 4 + it) * 256 + t) * 4;
            float4 tv = *(const float4*)(tm + idx);
            int4 av = *(const int4*)(adj + idx);
            float w0 = exp2f((tv.x - tmx) * C) * LOG2E;
            float w1 = exp2f((tv.y - tmx) * C) * LOG2E;
            float w2 = exp2f((tv.z - tmx) * C) * LOG2E;
            float w3 = exp2f((tv.w - tmx) * C) * LOG2E;
            unsigned int fa = av.x ? __float_as_uint(w0) : 0x7FC00000u;  // NaN when masked
            unsigned int fb = av.y ? __float_as_uint(w1) : 0x7FC00000u;
            unsigned int fc = av.z ? __float_as_uint(w2) : 0x7FC00000u;
            unsigned int fd = av.w ? __float_as_uint(w3) : 0x7FC00000u;
            uint2 pk;
            pk.x = __builtin_amdgcn_perm(fb, fa, 0x07060302);
            pk.y = __builtin_amdgcn_perm(fd, fc, 0x07060302);
            *(uint2*)&TWb[idx] = pk;
        }
    } else if (bx < 2176) {
        int g = bx - 2048;
        gemm1_body(node0b, Wt, ga, Ht1, es1, ed1, g & 15, g >> 4, t);
    } else {
        int idx = (bx - 2176) * 256 + t;
        if (idx < ZF4) ((float4*)zbase)[idx] = (float4){0.f, 0.f, 0.f, 0.f};
    }
}

// ============ kedge: E1[h][i][j] = bf16(leaky(es1_i + ed1_j)), batch-invariant ==========
__global__ __launch_bounds__(256) void kedge(const float* __restrict__ es, const float* __restrict__ ed,
                                             us* __restrict__ E1) {
    int g = blockIdx.x;             // 2048: h = g>>8, 4 i-rows per block
    int h = g >> 8, i0 = (g & 255) << 2;
    int t = threadIdx.x;
    __shared__ float eds[NT];
    *(float4*)&eds[t * 4] = *(const float4*)&ed[h * NT + t * 4];
    __syncthreads();
    int j = t * 4;
    float4 e4 = *(const float4*)&eds[j];
    #pragma unroll
    for (int r = 0; r < 4; r++) {
        float esv = es[h * NT + i0 + r];
        float a = esv + e4.x; a = fmaxf(a, 0.2f * a);
        float bq = esv + e4.y; bq = fmaxf(bq, 0.2f * bq);
        float c = esv + e4.z; c = fmaxf(c, 0.2f * c);
        float d = esv + e4.w; d = fmaxf(d, 0.2f * d);
        uint2 pk;
        pk.x = __builtin_amdgcn_perm(__float_as_uint(bq), __float_as_uint(a), 0x07060302);
        pk.y = __builtin_amdgcn_perm(__float_as_uint(d), __float_as_uint(c), 0x07060302);
        *(uint2*)&E1[((size_t)(h * NT) + i0 + r) * NT + j] = pk;
    }
}

// ============ kattn1: LDS-free, zero-barrier K-loop; A/B frags direct from global =======
__device__ __forceinline__ bf16x8 compute_p8(uint4 T, uint4 E) {
    union { uint4 v; unsigned int w[4]; } tu, eu;
    tu.v = T; eu.v = E;
    unsigned int pk[4];
    #pragma unroll
    for (int r = 0; r < 4; r++) {
        float twa = __uint_as_float(tu.w[r] << 16);
        float twb = __uint_as_float(tu.w[r] & 0xFFFF0000u);
        float Ea  = __uint_as_float(eu.w[r] << 16);
        float Eb  = __uint_as_float(eu.w[r] & 0xFFFF0000u);
        float pa = fmaxf(exp2f(twa * Ea), 0.f);   // NaN tw -> 0
        float pb = fmaxf(exp2f(twb * Eb), 0.f);
        pk[r] = __builtin_amdgcn_perm(__float_as_uint(pb), __float_as_uint(pa), 0x07060302);
    }
    union { uint4 v; bf16x8 b; } o;
    o.v = make_uint4(pk[0], pk[1], pk[2], pk[3]);
    return o.b;
}

__global__ __launch_bounds__(256) void kattn1(const us* __restrict__ TWb, const us* __restrict__ Ht,
                                              const us* __restrict__ E1, const float* __restrict__ ws2,
                                              const int* __restrict__ topic_ids,
                                              us* __restrict__ node1b, float* __restrict__ es2q) {
    int x = blockIdx.x; int iblk = x & 15; int b = x >> 4; int h = blockIdx.y;
    int t = threadIdx.x;
    int l = t & 63, w = t >> 6, m = l & 15, q = l >> 4;
    __shared__ float invl_s[64];
    int ia = iblk * 64 + w * 16 + m;            // A-frag row (lane-owned)
    const us* twrow = TWb + ((size_t)(b * NT) + ia) * NT + q * 8;
    const us* erow  = E1 + ((size_t)(h * NT) + ia) * NT + q * 8;
    const us* htrow = Ht + ((size_t)(h * HD) + m) * NT + q * 8;
    f32x4 acc[4];
    #pragma unroll
    for (int ot = 0; ot < 4; ot++) acc[ot] = (f32x4){0.f, 0.f, 0.f, 0.f};
    f32x4 acc1 = (f32x4){0.f, 0.f, 0.f, 0.f};   // ones-column: row sums of P
    short ov = (m == 0) ? (short)0x3F80 : (short)0;
    bf16x8 bones = {ov, ov, ov, ov, ov, ov, ov, ov};
    #pragma unroll 2
    for (int j0 = 0; j0 < NT; j0 += 32) {
        uint4 T = *(const uint4*)(twrow + j0);
        uint4 E = *(const uint4*)(erow + j0);
        bf16x8 b0 = *(const bf16x8*)(htrow + j0);
        bf16x8 b1 = *(const bf16x8*)(htrow + 16 * NT + j0);
        bf16x8 b2 = *(const bf16x8*)(htrow + 32 * NT + j0);
        bf16x8 b3 = *(const bf16x8*)(htrow + 48 * NT + j0);
        bf16x8 a = compute_p8(T, E);
        acc[0] = __builtin_amdgcn_mfma_f32_16x16x32_bf16(a, b0, acc[0], 0, 0, 0);
        acc[1] = __builtin_amdgcn_mfma_f32_16x16x32_bf16(a, b1, acc[1], 0, 0, 0);
        acc[2] = __builtin_amdgcn_mfma_f32_16x16x32_bf16(a, b2, acc[2], 0, 0, 0);
        acc[3] = __builtin_amdgcn_mfma_f32_16x16x32_bf16(a, b3, acc[3], 0, 0, 0);
        acc1   = __builtin_amdgcn_mfma_f32_16x16x32_bf16(a, bones, acc1, 0, 0, 0);
    }
    if (m == 0) {
        #pragma unroll
        for (int rr = 0; rr < 4; rr++) invl_s[w * 16 + q * 4 + rr] = 1.f / acc1[rr];
    }
    __syncthreads();
    float varr[4][4];
    #pragma unroll
    for (int ot = 0; ot < 4; ot++) {
        int col = h * HD + ot * 16 + m;
        #pragma unroll
        for (int rr = 0; rr < 4; rr++) {
            int i_loc = w * 16 + q * 4 + rr;
            float v = acc[ot][rr] * invl_s[i_loc];
            v = v > 0.f ? v : (__expf(v) - 1.f);  // ELU
            varr[ot][rr] = v;
            node1b[(size_t)(b * NT + iblk * 64 + i_loc) * HID + col] = f2bf(v);
        }
    }
    // es2q-lite: only the block/wave/q-group containing row qi projects onto ws2_src
    int qi = topic_ids[b];
    if ((qi >> 6) == iblk && w == ((qi & 63) >> 4) && q == ((qi >> 2) & 3)) {
        int rr = qi & 3;
        #pragma unroll
        for (int h2 = 0; h2 < NH; h2++) {
            float s = 0.f;
            #pragma unroll
            for (int ot = 0; ot < 4; ot++)
                s = fmaf(varr[ot][rr], ws2[h2 * HID + h * HD + ot * 16 + m], s);
            #pragma unroll
            for (int mask = 1; mask < 16; mask <<= 1) s += __shfl_xor(s, mask);
            if (m == 0) atomicAdd(&es2q[b * NH + h2], s);
        }
    }
}

// ==== kgemm2: LDS-free GEMM + fused layer-2 attention (ed_j computed locally) ===========
__global__ __launch_bounds__(256) void kgemm2(const us* __restrict__ node1b, const us* __restrict__ Wt2,
                                              const us* __restrict__ TWb, const float* __restrict__ ga2,
                                              const float* __restrict__ es2q,
                                              const int* __restrict__ topic_ids,
                                              float* __restrict__ pv, float* __restrict__ pl) {
    int x = blockIdx.x; int iblk = x & 15; int b = x >> 4; int h = blockIdx.y;
    int t = threadIdx.x;
    int l = t & 63, w = t >> 6, m = l & 15, q = l >> 4;
    __shared__ float pv_s[4][64];
    __shared__ float pl_s[4];
    const us* ar = node1b + ((size_t)(b * NT) + iblk * 64 + w * 16 + m) * HID + q * 8;
    const us* br = Wt2 + ((size_t)(h * HD) + m) * HID + q * 8;
    f32x4 acc[4];
    #pragma unroll
    for (int ot = 0; ot < 4; ot++) acc[ot] = (f32x4){0.f, 0.f, 0.f, 0.f};
    #pragma unroll 4
    for (int k0 = 0; k0 < HID; k0 += 32) {
        bf16x8 a = *(const bf16x8*)(ar + k0);
        acc[0] = __builtin_amdgcn_mfma_f32_16x16x32_bf16(a, *(const bf16x8*)(br + k0), acc[0], 0, 0, 0);
        acc[1] = __builtin_amdgcn_mfma_f32_16x16x32_bf16(a, *(const bf16x8*)(br + 16 * HID + k0), acc[1], 0, 0, 0);
        acc[2] = __builtin_amdgcn_mfma_f32_16x16x32_bf16(a, *(const bf16x8*)(br + 32 * HID + k0), acc[2], 0, 0, 0);
        acc[3] = __builtin_amdgcn_mfma_f32_16x16x32_bf16(a, *(const bf16x8*)(br + 48 * HID + k0), acc[3], 0, 0, 0);
    }
    // acc[ot][rr] = H2[j = iblk*64 + w*16 + q*4 + rr][o = h*64 + ot*16 + m]
    int qi = topic_ids[b];
    float es_q = es2q[b * NH + h];
    const float* gad = ga2 + h * 2 * HD + HD;   // a_dst for head h
    float gd[4];
    #pragma unroll
    for (int ot = 0; ot < 4; ot++) gd[ot] = gad[ot * 16 + m];
    float pvp[4] = {0.f, 0.f, 0.f, 0.f};
    float psum = 0.f;
    #pragma unroll
    for (int rr = 0; rr < 4; rr++) {
        float d = 0.f;
        #pragma unroll
        for (int ot = 0; ot < 4; ot++) d = fmaf(acc[ot][rr], gd[ot], d);
        #pragma unroll
        for (int mask = 1; mask < 16; mask <<= 1) d += __shfl_xor(d, mask);   // all lanes get ed_j
        int j = iblk * 64 + w * 16 + q * 4 + rr;
        float tw = bf2f(TWb[((size_t)(b * NT) + qi) * NT + j]);  // tw*log2e or NaN
        float e = es_q + d;
        e = fmaxf(e, 0.2f * e) * tw;
        float pj = fmaxf(exp2f(e), 0.f);   // NaN -> 0
        psum += pj;
        #pragma unroll
        for (int ot = 0; ot < 4; ot++) pvp[ot] = fmaf(pj, acc[ot][rr], pvp[ot]);
    }
    #pragma unroll
    for (int mask = 16; mask < 64; mask <<= 1) {
        psum += __shfl_xor(psum, mask);
        #pragma unroll
        for (int ot = 0; ot < 4; ot++) pvp[ot] += __shfl_xor(pvp[ot], mask);
    }
    if (q == 0) {
        #pragma unroll
        for (int ot = 0; ot < 4; ot++) pv_s[w][ot * 16 + m] = pvp[ot];
        if (m == 0) pl_s[w] = psum;
    }
    __syncthreads();
    if (t < 64) {
        float s = pv_s[0][t] + pv_s[1][t] + pv_s[2][t] + pv_s[3][t];
        atomicAdd(&pv[(size_t)(b * NH + h) * HD + t], s);
    }
    if (t == 0) atomicAdd(&pl[b * NH + h], pl_s[0] + pl_s[1] + pl_s[2] + pl_s[3]);
}

// ============ khead2: 256 blocks (kseg 32 x b 8); atomicAdd partials into out[b] ========
__global__ __launch_bounds__(256) void khead2(const float* __restrict__ pv, const float* __restrict__ pl,
                                              const float* __restrict__ attr,
                                              const float* __restrict__ aW, const float* __restrict__ ab,
                                              const float* __restrict__ fc1W, const float* __restrict__ fc1b,
                                              const float* __restrict__ fc2W, float* __restrict__ out) {
    int kseg = blockIdx.x, b = blockIdx.y;
    int t = threadIdx.x;
    __shared__ float comb[HID];
    __shared__ float linv[NH];
    __shared__ float r2[256];
    if (t < NH) linv[t] = 1.f / pl[b * NH + t];
    __syncthreads();
    float av = attr[b];
    for (int k = t; k < HID; k += 256) {
        int h = k >> 6, o = k & 63;
        float v = pv[(size_t)(b * NH + h) * HD + o] * linv[h];
        v = v > 0.f ? v : (__expf(v) - 1.f);  // ELU
        comb[k] = v + av * aW[k] + ab[k];
    }
    __syncthreads();
    int kk = kseg * 16 + (t >> 4);
    int j = t & 15;
    const float* row = fc1W + (size_t)kk * HID;
    float acc = 0.f;
    #pragma unroll 8
    for (int mi = 0; mi < 32; mi++) {
        int idx = mi * 16 + j;
        acc = fmaf(comb[idx], row[idx], acc);
    }
    #pragma unroll
    for (int mask = 1; mask < 16; mask <<= 1) acc += __shfl_xor(acc, mask);
    float partv = 0.f;
    if (j == 0) {
        float hk = fmaxf(acc + fc1b[kk], 0.f);
        partv = hk * fc2W[kk];
    }
    r2[t] = partv; __syncthreads();
    for (int s = 128; s > 0; s >>= 1) { if (t < s) r2[t] += r2[t + s]; __syncthreads(); }
    if (t == 0) atomicAdd(&out[b], r2[0]);
}

extern "C" void kernel_launch(void* const* d_in, const int* in_sizes, int n_in,
                              void* d_out, int out_size, void* d_ws, size_t ws_size,
                              hipStream_t stream) {
    const int*   topic_ids = (const int*)d_in[0];
    const int*   adj       = (const int*)d_in[1];
    const float* tm        = (const float*)d_in[2];
    const float* attr      = (const float*)d_in[3];
    const float* emb       = (const float*)d_in[4];
    const float* sW        = (const float*)d_in[5];
    const float* sb        = (const float*)d_in[6];
    const float* aW        = (const float*)d_in[7];
    const float* ab        = (const float*)d_in[8];
    const float* gW        = (const float*)d_in[9];   // (2,8,512,64)
    const float* ga        = (const float*)d_in[10];  // (2,8,128,1)
    const float* fc1W      = (const float*)d_in[11];
    const float* fc1b      = (const float*)d_in[12];
    const float* fc2W      = (const float*)d_in[13];
    const float* fc2b      = (const float*)d_in[14];
    float* out = (float*)d_out;

    char* p = (char*)d_ws;
    us* TWb    = (us*)p; p += sizeof(us) * (size_t)NB * NT * NT;        // 16.8 MB
    us* E1     = (us*)p; p += sizeof(us) * (size_t)NH * NT * NT;        // 16.8 MB
    us* node0b = (us*)p; p += sizeof(us) * (size_t)NT * HID;            // 1 MB
    us* Wt     = (us*)p; p += sizeof(us) * (size_t)2 * NH * HD * HID;   // 1 MB
    us* Ht1    = (us*)p; p += sizeof(us) * (size_t)HID * NT;            // 1 MB
    us* node1b = (us*)p; p += sizeof(us) * (size_t)NB * NT * HID;       // 8 MB
    float* es1  = (float*)p; p += sizeof(float) * NH * NT;
    float* ed1  = (float*)p; p += sizeof(float) * NH * NT;
    // zero region (contiguous): es2q, pv, pl
    float* es2q = (float*)p; p += sizeof(float) * NB * NH;              // 256 B
    float* pv   = (float*)p; p += sizeof(float) * NB * NH * HD;         // 16 KB
    float* pl   = (float*)p; p += sizeof(float) * NB * NH;              // 256 B
    float* ws2  = (float*)p; p += sizeof(float) * 16 * HID;             // 32 KB
    float* part = (float*)p; p += sizeof(float) * 1024;

    kprep<<<1288, 256, 0, stream>>>(tm, part, emb, sW, sb, node0b, gW, Wt, ga, ws2, fc2b, out);
    kphase1<<<2181, 256, 0, stream>>>(tm, adj, part, TWb, node0b, Wt, ga, Ht1, es1, ed1, es2q);
    kedge<<<2048, 256, 0, stream>>>(es1, ed1, E1);
    kattn1<<<dim3(16 * NB, NH), 256, 0, stream>>>(TWb, Ht1, E1, ws2, topic_ids, node1b, es2q);
    kgemm2<<<dim3(16 * NB, NH), 256, 0, stream>>>(node1b, Wt + (size_t)NH * HD * HID, TWb,
                                                  ga + NH * 2 * HD, es2q, topic_ids, pv, pl);
    khead2<<<dim3(32, NB), 256, 0, stream>>>(pv, pl, attr, aW, ab, fc1W, fc1b, fc2W, out);
}

// Round 13
// 204.689 us; speedup vs baseline: 1.4265x; 1.4265x over previous
//
#include <hip/hip_runtime.h>

#define NT 1024      // N_TOPICS
#define TD 128       // TOPIC_DIM
#define HID 512      // HIDDEN
#define NH 8         // N_HEADS
#define HD 64        // HEAD_DIM
#define NB 8         // BATCH

typedef unsigned short us;
typedef short bf16x8 __attribute__((ext_vector_type(8)));
typedef float f32x4 __attribute__((ext_vector_type(4)));

#define LOG2E 1.44269504f

__device__ __forceinline__ us f2bf(float x) {
    unsigned int u = __float_as_uint(x);
    return (us)((u + 0x7FFFu + ((u >> 16) & 1u)) >> 16);
}
__device__ __forceinline__ float bf2f(us s) {
    return __uint_as_float(((unsigned int)s) << 16);
}

// ==== kprep: kmax (0-1023) | node0 MFMA (1024-1151) | gW transpose (1152-1279) | ws2 (1280-1287)
__global__ __launch_bounds__(256) void kprep(const float* __restrict__ tm, float* __restrict__ part,
                                             const float* __restrict__ emb, const float* __restrict__ sW,
                                             const float* __restrict__ sb, us* __restrict__ node0b,
                                             const float* __restrict__ gW, us* __restrict__ Wt,
                                             const float* __restrict__ ga, float* __restrict__ ws2,
                                             const float* __restrict__ fc2b, float* __restrict__ out) {
    __shared__ __align__(16) float smf[8768];   // 35 KB shared by branches
    int bx = blockIdx.x, t = threadIdx.x;
    if (bx < 1024) {
        const float4* tm4 = (const float4*)tm;
        size_t base = (size_t)bx * 256 + t;
        float m = -1e30f;
        #pragma unroll
        for (int k = 0; k < 8; k++) {
            float4 v = tm4[base + (size_t)k * 262144];
            m = fmaxf(m, fmaxf(fmaxf(v.x, v.y), fmaxf(v.z, v.w)));
        }
        smf[t] = m; __syncthreads();
        for (int s = 128; s > 0; s >>= 1) { if (t < s) smf[t] = fmaxf(smf[t], smf[t + s]); __syncthreads(); }
        if (t == 0) part[bx] = smf[0];
    } else if (bx < 1152) {
        // node0 = emb @ sW^T + sb via MFMA. block: (iblk 16) x (oseg 8); K=128, one barrier.
        int g = bx - 1024; int iblk = g & 15, oseg = g >> 4;
        us* As = (us*)smf;              // [64][136]
        us* Bs = (us*)smf + 64 * 136;   // [64][136]
        const float4* esrc = (const float4*)(emb + (size_t)iblk * 64 * TD);
        const float4* wsrc = (const float4*)(sW + (size_t)oseg * 64 * TD);
        #pragma unroll
        for (int rep = 0; rep < 8; rep++) {
            int f = rep * 256 + t;
            int row = f >> 5, c4 = f & 31;
            float4 av = esrc[f];
            float4 bv = wsrc[f];
            us pa[4] = {f2bf(av.x), f2bf(av.y), f2bf(av.z), f2bf(av.w)};
            us pb[4] = {f2bf(bv.x), f2bf(bv.y), f2bf(bv.z), f2bf(bv.w)};
            *(uint2*)&As[row * 136 + c4 * 4] = *(uint2*)pa;
            *(uint2*)&Bs[row * 136 + c4 * 4] = *(uint2*)pb;
        }
        __syncthreads();
        int l = t & 63, w = t >> 6, m = l & 15, q = l >> 4;
        f32x4 acc[4];
        #pragma unroll
        for (int ot = 0; ot < 4; ot++) acc[ot] = (f32x4){0.f, 0.f, 0.f, 0.f};
        #pragma unroll
        for (int ks = 0; ks < 4; ks++) {
            bf16x8 a = *(const bf16x8*)&As[(w * 16 + m) * 136 + ks * 32 + q * 8];
            #pragma unroll
            for (int ot = 0; ot < 4; ot++) {
                bf16x8 b = *(const bf16x8*)&Bs[(ot * 16 + m) * 136 + ks * 32 + q * 8];
                acc[ot] = __builtin_amdgcn_mfma_f32_16x16x32_bf16(a, b, acc[ot], 0, 0, 0);
            }
        }
        #pragma unroll
        for (int ot = 0; ot < 4; ot++) {
            int col = oseg * 64 + ot * 16 + m;
            float sbv = sb[col];
            #pragma unroll
            for (int rr = 0; rr < 4; rr++) {
                int rowi = iblk * 64 + w * 16 + q * 4 + rr;
                node0b[(size_t)rowi * HID + col] = f2bf(acc[ot][rr] + sbv);
            }
        }
    } else if (bx < 1280) {
        // Wt[lh][o][k] = bf16(gW[lh][k][o]) via LDS tile transpose
        int g = bx - 1152; int lh = g >> 3, kt = g & 7;
        float* tile = smf;   // [64][65]
        const float4* src = (const float4*)(gW + ((size_t)lh * HID + kt * 64) * HD);
        #pragma unroll
        for (int rep = 0; rep < 4; rep++) {
            int f = rep * 256 + t;
            float4 v = src[f];
            int row = f >> 4, col = (f & 15) * 4;
            float* d = tile + row * 65 + col;
            d[0] = v.x; d[1] = v.y; d[2] = v.z; d[3] = v.w;
        }
        __syncthreads();
        int o = t >> 2, ks = (t & 3) * 16;
        us pk[16];
        #pragma unroll
        for (int j = 0; j < 16; j++) pk[j] = f2bf(tile[(ks + j) * 65 + o]);
        us* dst = Wt + (size_t)lh * HD * HID + (size_t)o * HID + kt * 64 + ks;
        *(uint4*)dst = *(uint4*)pk;
        *(uint4*)(dst + 8) = *(uint4*)&pk[8];
    } else {
        // ws2[h'][k] = sum_o gW2[h'][k][o]*a2src[o]; ws2[8+h'][k] = ... a2dst[o]
        int hp = bx - 1280;   // 0..7
        if (hp == 0 && t < NB) out[t] = fc2b[0];   // init for khead2 atomics
        const float* gsrc = ga + (size_t)(NH + hp) * 2 * HD;
        const float* wbase = gW + (size_t)(NH + hp) * HID * HD;
        #pragma unroll
        for (int rep = 0; rep < 2; rep++) {
            int k = rep * 256 + t;
            const float* wr = wbase + (size_t)k * HD;
            float s = 0.f, d = 0.f;
            #pragma unroll 8
            for (int o = 0; o < HD; o++) {
                float wv = wr[o];
                s = fmaf(wv, gsrc[o], s);
                d = fmaf(wv, gsrc[HD + o], d);
            }
            ws2[hp * HID + k] = s;
            ws2[(8 + hp) * HID + k] = d;
        }
    }
}

// ============ LDS-staged layer-1 GEMM body: 64x64, BK=64, dbuf, dist-2 (R10-proven) =====
__device__ __forceinline__ void gemm1_body(const us* __restrict__ A, const us* __restrict__ W,
                                           const float* __restrict__ gav, us* __restrict__ outT,
                                           float* __restrict__ esO, float* __restrict__ edO,
                                           int iblk, int h, int t, us* sm) {
    us* As = sm;              // [2][64*72]
    us* Bs = sm + 2 * 4608;   // [2][64*72]
    int row = t >> 2, ks = t & 3;
    int l = t & 63, w = t >> 6, m = l & 15, q = l >> 4;
    const us* ar = A + ((size_t)(iblk * 64 + row)) * HID + ks * 16;
    const us* br = W + ((size_t)(h * HD + row)) * HID + ks * 16;
    f32x4 acc[4];
    #pragma unroll
    for (int ot = 0; ot < 4; ot++) acc[ot] = (f32x4){0.f, 0.f, 0.f, 0.f};
    {
        uint4 x0 = *(const uint4*)ar, x1 = *(const uint4*)(ar + 8);
        uint4 y0 = *(const uint4*)br, y1 = *(const uint4*)(br + 8);
        *(uint4*)&As[row * 72 + ks * 16] = x0; *(uint4*)&As[row * 72 + ks * 16 + 8] = x1;
        *(uint4*)&Bs[row * 72 + ks * 16] = y0; *(uint4*)&Bs[row * 72 + ks * 16 + 8] = y1;
    }
    uint4 a0 = *(const uint4*)(ar + 64), a1 = *(const uint4*)(ar + 72);
    uint4 b0 = *(const uint4*)(br + 64), b1 = *(const uint4*)(br + 72);
    for (int it = 0; it < 8; it++) {
        int cur = it & 1, nxt = cur ^ 1;
        uint4 na0, na1, nb0, nb1;
        if (it < 6) {
            int k0 = (it + 2) * 64;
            na0 = *(const uint4*)(ar + k0); na1 = *(const uint4*)(ar + k0 + 8);
            nb0 = *(const uint4*)(br + k0); nb1 = *(const uint4*)(br + k0 + 8);
        }
        __syncthreads();
        if (it < 7) {
            *(uint4*)&As[nxt * 4608 + row * 72 + ks * 16] = a0;
            *(uint4*)&As[nxt * 4608 + row * 72 + ks * 16 + 8] = a1;
            *(uint4*)&Bs[nxt * 4608 + row * 72 + ks * 16] = b0;
            *(uint4*)&Bs[nxt * 4608 + row * 72 + ks * 16 + 8] = b1;
        }
        const us* Ac = As + cur * 4608; const us* Bc = Bs + cur * 4608;
        #pragma unroll
        for (int kt = 0; kt < 2; kt++) {
            bf16x8 av = *(const bf16x8*)&Ac[(w * 16 + m) * 72 + kt * 32 + q * 8];
            #pragma unroll
            for (int ot = 0; ot < 4; ot++) {
                bf16x8 bv = *(const bf16x8*)&Bc[(ot * 16 + m) * 72 + kt * 32 + q * 8];
                acc[ot] = __builtin_amdgcn_mfma_f32_16x16x32_bf16(av, bv, acc[ot], 0, 0, 0);
            }
        }
        if (it < 6) { a0 = na0; a1 = na1; b0 = nb0; b1 = nb1; }
    }
    const float* gas = gav + h * 2 * HD;
    float gs[4], gd[4];
    #pragma unroll
    for (int ot = 0; ot < 4; ot++) { gs[ot] = gas[ot * 16 + m]; gd[ot] = gas[HD + ot * 16 + m]; }
    #pragma unroll
    for (int rr = 0; rr < 4; rr++) {
        float s = 0.f, d = 0.f;
        #pragma unroll
        for (int ot = 0; ot < 4; ot++) { float v = acc[ot][rr]; s = fmaf(v, gs[ot], s); d = fmaf(v, gd[ot], d); }
        #pragma unroll
        for (int mask = 1; mask < 16; mask <<= 1) { s += __shfl_xor(s, mask); d += __shfl_xor(d, mask); }
        if (m == 0) {
            int rowi = iblk * 64 + w * 16 + q * 4 + rr;
            esO[h * NT + rowi] = s;
            edO[h * NT + rowi] = d;
        }
    }
    #pragma unroll
    for (int ot = 0; ot < 4; ot++) {
        int col = h * HD + ot * 16 + m;
        #pragma unroll
        for (int rr = 0; rr < 4; rr++) {
            int i_loc = iblk * 64 + w * 16 + q * 4 + rr;
            outT[(size_t)col * NT + i_loc] = f2bf(acc[ot][rr]);
        }
    }
}

// ==== kphase1: ktw (0-2047) | layer-1 GEMM (2048-2175) | zero es2q/pv/pl (2176-2180) ====
#define ZF4 1056   // (64+4096+64)/4 float4s to zero
__global__ __launch_bounds__(256) void kphase1(const float* __restrict__ tm, const int* __restrict__ adj,
                                               const float* __restrict__ part, us* __restrict__ TWb,
                                               const us* __restrict__ node0b, const us* __restrict__ Wt,
                                               const float* __restrict__ ga, us* __restrict__ Ht1,
                                               float* __restrict__ es1, float* __restrict__ ed1,
                                               float* __restrict__ zbase) {
    __shared__ __align__(16) us sm[4 * 4608];
    int bx = blockIdx.x, t = threadIdx.x;
    if (bx < 2048) {
        float* red = (float*)sm;
        float m = fmaxf(fmaxf(part[t * 4], part[t * 4 + 1]), fmaxf(part[t * 4 + 2], part[t * 4 + 3]));
        red[t] = m; __syncthreads();
        for (int s = 128; s > 0; s >>= 1) { if (t < s) red[t] = fmaxf(red[t], red[t + s]); __syncthreads(); }
        float tmx = red[0];
        const float C = 0.1f * LOG2E;
        #pragma unroll
        for (int it = 0; it < 4; it++) {
            size_t idx = (((size_t)bx * 4 + it) * 256 + t) * 4;
            float4 tv = *(const float4*)(tm + idx);
            int4 av = *(const int4*)(adj + idx);
            float w0 = exp2f((tv.x - tmx) * C) * LOG2E;
            float w1 = exp2f((tv.y - tmx) * C) * LOG2E;
            float w2 = exp2f((tv.z - tmx) * C) * LOG2E;
            float w3 = exp2f((tv.w - tmx) * C) * LOG2E;
            unsigned int fa = av.x ? __float_as_uint(w0) : 0x7FC00000u;  // NaN when masked
            unsigned int fb = av.y ? __float_as_uint(w1) : 0x7FC00000u;
            unsigned int fc = av.z ? __float_as_uint(w2) : 0x7FC00000u;
            unsigned int fd = av.w ? __float_as_uint(w3) : 0x7FC00000u;
            uint2 pk;
            pk.x = __builtin_amdgcn_perm(fb, fa, 0x07060302);
            pk.y = __builtin_amdgcn_perm(fd, fc, 0x07060302);
            *(uint2*)&TWb[idx] = pk;
        }
    } else if (bx < 2176) {
        int g = bx - 2048;
        gemm1_body(node0b, Wt, ga, Ht1, es1, ed1, g & 15, g >> 4, t, sm);
    } else {
        int idx = (bx - 2176) * 256 + t;
        if (idx < ZF4) ((float4*)zbase)[idx] = (float4){0.f, 0.f, 0.f, 0.f};
    }
}

// ============ kedge: E1[h][i][j] = bf16(leaky(es1_i + ed1_j)), batch-invariant ==========
__global__ __launch_bounds__(256) void kedge(const float* __restrict__ es, const float* __restrict__ ed,
                                             us* __restrict__ E1) {
    int g = blockIdx.x;             // 2048: h = g>>8, 4 i-rows per block
    int h = g >> 8, i0 = (g & 255) << 2;
    int t = threadIdx.x;
    __shared__ float eds[NT];
    *(float4*)&eds[t * 4] = *(const float4*)&ed[h * NT + t * 4];
    __syncthreads();
    int j = t * 4;
    float4 e4 = *(const float4*)&eds[j];
    #pragma unroll
    for (int r = 0; r < 4; r++) {
        float esv = es[h * NT + i0 + r];
        float a = esv + e4.x; a = fmaxf(a, 0.2f * a);
        float bq = esv + e4.y; bq = fmaxf(bq, 0.2f * bq);
        float c = esv + e4.z; c = fmaxf(c, 0.2f * c);
        float d = esv + e4.w; d = fmaxf(d, 0.2f * d);
        uint2 pk;
        pk.x = __builtin_amdgcn_perm(__float_as_uint(bq), __float_as_uint(a), 0x07060302);
        pk.y = __builtin_amdgcn_perm(__float_as_uint(d), __float_as_uint(c), 0x07060302);
        *(uint2*)&E1[((size_t)(h * NT) + i0 + r) * NT + j] = pk;
    }
}

// ============ kattn1: LDS dbuf dist-2 (R10-proven) + es2q-lite epilogue =================
__device__ __forceinline__ void compute_p(uint4 T0, uint4 T1, uint4 E0, uint4 E1v,
                                          uint4& P01, uint4& P23) {
    union U { uint4 v; unsigned int w[4]; };
    U t0; t0.v = T0; U t1; t1.v = T1; U e0; e0.v = E0; U e1; e1.v = E1v;
    unsigned int pk[8];
    #pragma unroll
    for (int r = 0; r < 4; r++) {
        float twa = __uint_as_float(t0.w[r] << 16);
        float twb = __uint_as_float(t0.w[r] & 0xFFFF0000u);
        float Ea  = __uint_as_float(e0.w[r] << 16);
        float Eb  = __uint_as_float(e0.w[r] & 0xFFFF0000u);
        float pa = fmaxf(exp2f(twa * Ea), 0.f);   // NaN tw -> 0
        float pb = fmaxf(exp2f(twb * Eb), 0.f);
        pk[r] = __builtin_amdgcn_perm(__float_as_uint(pb), __float_as_uint(pa), 0x07060302);
    }
    #pragma unroll
    for (int r = 0; r < 4; r++) {
        float twa = __uint_as_float(t1.w[r] << 16);
        float twb = __uint_as_float(t1.w[r] & 0xFFFF0000u);
        float Ea  = __uint_as_float(e1.w[r] << 16);
        float Eb  = __uint_as_float(e1.w[r] & 0xFFFF0000u);
        float pa = fmaxf(exp2f(twa * Ea), 0.f);
        float pb = fmaxf(exp2f(twb * Eb), 0.f);
        pk[4 + r] = __builtin_amdgcn_perm(__float_as_uint(pb), __float_as_uint(pa), 0x07060302);
    }
    P01 = make_uint4(pk[0], pk[1], pk[2], pk[3]);
    P23 = make_uint4(pk[4], pk[5], pk[6], pk[7]);
}

__global__ __launch_bounds__(256) void kattn1(const us* __restrict__ TWb, const us* __restrict__ Ht,
                                              const us* __restrict__ E1, const float* __restrict__ ws2,
                                              const int* __restrict__ topic_ids,
                                              us* __restrict__ node1b, float* __restrict__ es2q) {
    int x = blockIdx.x; int iblk = x & 15; int b = x >> 4; int h = blockIdx.y;
    int t = threadIdx.x;
    __shared__ __align__(16) us Ps[2 * 4608];
    __shared__ __align__(16) us Hs[2 * 4608];
    __shared__ float invl_s[64];
    int i = t >> 2, js = t & 3;
    int l = t & 63, w = t >> 6, m = l & 15, q = l >> 4;
    const us* twrow = TWb + ((size_t)(b * NT) + iblk * 64 + i) * NT + js * 16;
    const us* erow  = E1 + ((size_t)(h * NT) + iblk * 64 + i) * NT + js * 16;
    const us* htrow = Ht + ((size_t)(h * HD) + i) * NT + js * 16;
    f32x4 acc[4];
    #pragma unroll
    for (int ot = 0; ot < 4; ot++) acc[ot] = (f32x4){0.f, 0.f, 0.f, 0.f};
    f32x4 acc1 = (f32x4){0.f, 0.f, 0.f, 0.f};       // ones-column: row sums of P
    short ov = (m == 0) ? (short)0x3F80 : (short)0;
    bf16x8 bones = {ov, ov, ov, ov, ov, ov, ov, ov};
    uint4 T0, T1, E0, E1r, Hh0, Hh1;
    T0 = *(const uint4*)twrow; T1 = *(const uint4*)(twrow + 8);
    E0 = *(const uint4*)erow;  E1r = *(const uint4*)(erow + 8);
    Hh0 = *(const uint4*)htrow; Hh1 = *(const uint4*)(htrow + 8);
    {
        uint4 p01, p23;
        compute_p(T0, T1, E0, E1r, p01, p23);
        us* Pd = Ps + i * 72 + js * 16;
        us* Hd = Hs + i * 72 + js * 16;
        *(uint4*)Pd = p01; *(uint4*)(Pd + 8) = p23;
        *(uint4*)Hd = Hh0; *(uint4*)(Hd + 8) = Hh1;
    }
    T0 = *(const uint4*)(twrow + 64); T1 = *(const uint4*)(twrow + 72);
    E0 = *(const uint4*)(erow + 64);  E1r = *(const uint4*)(erow + 72);
    Hh0 = *(const uint4*)(htrow + 64); Hh1 = *(const uint4*)(htrow + 72);
    for (int it = 0; it < 16; it++) {
        int cur = it & 1, nxt = cur ^ 1;
        uint4 nT0, nT1, nE0, nE1, nH0, nH1;
        if (it < 14) {
            int j0 = (it + 2) * 64;
            nT0 = *(const uint4*)(twrow + j0); nT1 = *(const uint4*)(twrow + j0 + 8);
            nE0 = *(const uint4*)(erow + j0);  nE1 = *(const uint4*)(erow + j0 + 8);
            nH0 = *(const uint4*)(htrow + j0); nH1 = *(const uint4*)(htrow + j0 + 8);
        }
        uint4 p01, p23;
        if (it < 15) compute_p(T0, T1, E0, E1r, p01, p23);
        __syncthreads();
        if (it < 15) {
            us* Pd = Ps + nxt * 4608 + i * 72 + js * 16;
            us* Hd = Hs + nxt * 4608 + i * 72 + js * 16;
            *(uint4*)Pd = p01; *(uint4*)(Pd + 8) = p23;
            *(uint4*)Hd = Hh0; *(uint4*)(Hd + 8) = Hh1;
        }
        const us* Pc = Ps + cur * 4608; const us* Hc = Hs + cur * 4608;
        #pragma unroll
        for (int kt = 0; kt < 2; kt++) {
            bf16x8 av = *(const bf16x8*)&Pc[(w * 16 + m) * 72 + kt * 32 + q * 8];
            #pragma unroll
            for (int ot = 0; ot < 4; ot++) {
                bf16x8 bv = *(const bf16x8*)&Hc[(ot * 16 + m) * 72 + kt * 32 + q * 8];
                acc[ot] = __builtin_amdgcn_mfma_f32_16x16x32_bf16(av, bv, acc[ot], 0, 0, 0);
            }
            acc1 = __builtin_amdgcn_mfma_f32_16x16x32_bf16(av, bones, acc1, 0, 0, 0);
        }
        if (it < 14) { T0 = nT0; T1 = nT1; E0 = nE0; E1r = nE1; Hh0 = nH0; Hh1 = nH1; }
    }
    if (m == 0) {
        #pragma unroll
        for (int rr = 0; rr < 4; rr++) invl_s[w * 16 + q * 4 + rr] = 1.f / acc1[rr];
    }
    __syncthreads();
    float varr[4][4];
    #pragma unroll
    for (int ot = 0; ot < 4; ot++) {
        int col = h * HD + ot * 16 + m;
        #pragma unroll
        for (int rr = 0; rr < 4; rr++) {
            int i_loc = w * 16 + q * 4 + rr;
            float v = acc[ot][rr] * invl_s[i_loc];
            v = v > 0.f ? v : (__expf(v) - 1.f);  // ELU
            varr[ot][rr] = v;
            node1b[(size_t)(b * NT + iblk * 64 + i_loc) * HID + col] = f2bf(v);
        }
    }
    // es2q-lite: only the block/wave/q-group containing row qi projects onto ws2_src
    int qi = topic_ids[b];
    if ((qi >> 6) == iblk && w == ((qi & 63) >> 4) && q == ((qi >> 2) & 3)) {
        int rr = qi & 3;
        #pragma unroll
        for (int h2 = 0; h2 < NH; h2++) {
            float s = 0.f;
            #pragma unroll
            for (int ot = 0; ot < 4; ot++)
                s = fmaf(varr[ot][rr], ws2[h2 * HID + h * HD + ot * 16 + m], s);
            #pragma unroll
            for (int mask = 1; mask < 16; mask <<= 1) s += __shfl_xor(s, mask);
            if (m == 0) atomicAdd(&es2q[b * NH + h2], s);
        }
    }
}

// ==== kgemm2: LDS-staged GEMM + fused layer-2 attention epilogue (local ed_j) ===========
__global__ __launch_bounds__(256) void kgemm2(const us* __restrict__ node1b, const us* __restrict__ Wt2,
                                              const us* __restrict__ TWb, const float* __restrict__ ga2,
                                              const float* __restrict__ es2q,
                                              const int* __restrict__ topic_ids,
                                              float* __restrict__ pv, float* __restrict__ pl) {
    __shared__ __align__(16) us sm[4 * 4608];
    __shared__ float pv_s[4][64];
    __shared__ float pl_s[4];
    int x = blockIdx.x; int iblk = x & 15; int b = x >> 4; int h = blockIdx.y;
    int t = threadIdx.x;
    us* As = sm;
    us* Bs = sm + 2 * 4608;
    int row = t >> 2, ks = t & 3;
    int l = t & 63, w = t >> 6, m = l & 15, q = l >> 4;
    const us* ar = node1b + ((size_t)(b * NT) + iblk * 64 + row) * HID + ks * 16;
    const us* br = Wt2 + ((size_t)(h * HD + row)) * HID + ks * 16;
    f32x4 acc[4];
    #pragma unroll
    for (int ot = 0; ot < 4; ot++) acc[ot] = (f32x4){0.f, 0.f, 0.f, 0.f};
    {
        uint4 x0 = *(const uint4*)ar, x1 = *(const uint4*)(ar + 8);
        uint4 y0 = *(const uint4*)br, y1 = *(const uint4*)(br + 8);
        *(uint4*)&As[row * 72 + ks * 16] = x0; *(uint4*)&As[row * 72 + ks * 16 + 8] = x1;
        *(uint4*)&Bs[row * 72 + ks * 16] = y0; *(uint4*)&Bs[row * 72 + ks * 16 + 8] = y1;
    }
    uint4 a0 = *(const uint4*)(ar + 64), a1 = *(const uint4*)(ar + 72);
    uint4 b0 = *(const uint4*)(br + 64), b1 = *(const uint4*)(br + 72);
    for (int it = 0; it < 8; it++) {
        int cur = it & 1, nxt = cur ^ 1;
        uint4 na0, na1, nb0, nb1;
        if (it < 6) {
            int k0 = (it + 2) * 64;
            na0 = *(const uint4*)(ar + k0); na1 = *(const uint4*)(ar + k0 + 8);
            nb0 = *(const uint4*)(br + k0); nb1 = *(const uint4*)(br + k0 + 8);
        }
        __syncthreads();
        if (it < 7) {
            *(uint4*)&As[nxt * 4608 + row * 72 + ks * 16] = a0;
            *(uint4*)&As[nxt * 4608 + row * 72 + ks * 16 + 8] = a1;
            *(uint4*)&Bs[nxt * 4608 + row * 72 + ks * 16] = b0;
            *(uint4*)&Bs[nxt * 4608 + row * 72 + ks * 16 + 8] = b1;
        }
        const us* Ac = As + cur * 4608; const us* Bc = Bs + cur * 4608;
        #pragma unroll
        for (int kt = 0; kt < 2; kt++) {
            bf16x8 av = *(const bf16x8*)&Ac[(w * 16 + m) * 72 + kt * 32 + q * 8];
            #pragma unroll
            for (int ot = 0; ot < 4; ot++) {
                bf16x8 bv = *(const bf16x8*)&Bc[(ot * 16 + m) * 72 + kt * 32 + q * 8];
                acc[ot] = __builtin_amdgcn_mfma_f32_16x16x32_bf16(av, bv, acc[ot], 0, 0, 0);
            }
        }
        if (it < 6) { a0 = na0; a1 = na1; b0 = nb0; b1 = nb1; }
    }
    // acc[ot][rr] = H2[j = iblk*64 + w*16 + q*4 + rr][o = h*64 + ot*16 + m]
    int qi = topic_ids[b];
    float es_q = es2q[b * NH + h];
    const float* gad = ga2 + h * 2 * HD + HD;   // a_dst for head h
    float gd[4];
    #pragma unroll
    for (int ot = 0; ot < 4; ot++) gd[ot] = gad[ot * 16 + m];
    float pvp[4] = {0.f, 0.f, 0.f, 0.f};
    float psum = 0.f;
    #pragma unroll
    for (int rr = 0; rr < 4; rr++) {
        float d = 0.f;
        #pragma unroll
        for (int ot = 0; ot < 4; ot++) d = fmaf(acc[ot][rr], gd[ot], d);
        #pragma unroll
        for (int mask = 1; mask < 16; mask <<= 1) d += __shfl_xor(d, mask);   // all lanes get ed_j
        int j = iblk * 64 + w * 16 + q * 4 + rr;
        float tw = bf2f(TWb[((size_t)(b * NT) + qi) * NT + j]);  // tw*log2e or NaN
        float e = es_q + d;
        e = fmaxf(e, 0.2f * e) * tw;
        float pj = fmaxf(exp2f(e), 0.f);   // NaN -> 0
        psum += pj;
        #pragma unroll
        for (int ot = 0; ot < 4; ot++) pvp[ot] = fmaf(pj, acc[ot][rr], pvp[ot]);
    }
    #pragma unroll
    for (int mask = 16; mask < 64; mask <<= 1) {
        psum += __shfl_xor(psum, mask);
        #pragma unroll
        for (int ot = 0; ot < 4; ot++) pvp[ot] += __shfl_xor(pvp[ot], mask);
    }
    if (q == 0) {
        #pragma unroll
        for (int ot = 0; ot < 4; ot++) pv_s[w][ot * 16 + m] = pvp[ot];
        if (m == 0) pl_s[w] = psum;
    }
    __syncthreads();
    if (t < 64) {
        float s = pv_s[0][t] + pv_s[1][t] + pv_s[2][t] + pv_s[3][t];
        atomicAdd(&pv[(size_t)(b * NH + h) * HD + t], s);
    }
    if (t == 0) atomicAdd(&pl[b * NH + h], pl_s[0] + pl_s[1] + pl_s[2] + pl_s[3]);
}

// ============ khead2: 256 blocks (kseg 32 x b 8); atomicAdd partials into out[b] ========
__global__ __launch_bounds__(256) void khead2(const float* __restrict__ pv, const float* __restrict__ pl,
                                              const float* __restrict__ attr,
                                              const float* __restrict__ aW, const float* __restrict__ ab,
                                              const float* __restrict__ fc1W, const float* __restrict__ fc1b,
                                              const float* __restrict__ fc2W, float* __restrict__ out) {
    int kseg = blockIdx.x, b = blockIdx.y;
    int t = threadIdx.x;
    __shared__ float comb[HID];
    __shared__ float linv[NH];
    __shared__ float r2[256];
    if (t < NH) linv[t] = 1.f / pl[b * NH + t];
    __syncthreads();
    float av = attr[b];
    for (int k = t; k < HID; k += 256) {
        int h = k >> 6, o = k & 63;
        float v = pv[(size_t)(b * NH + h) * HD + o] * linv[h];
        v = v > 0.f ? v : (__expf(v) - 1.f);  // ELU
        comb[k] = v + av * aW[k] + ab[k];
    }
    __syncthreads();
    int kk = kseg * 16 + (t >> 4);
    int j = t & 15;
    const float* row = fc1W + (size_t)kk * HID;
    float acc = 0.f;
    #pragma unroll 8
    for (int mi = 0; mi < 32; mi++) {
        int idx = mi * 16 + j;
        acc = fmaf(comb[idx], row[idx], acc);
    }
    #pragma unroll
    for (int mask = 1; mask < 16; mask <<= 1) acc += __shfl_xor(acc, mask);
    float partv = 0.f;
    if (j == 0) {
        float hk = fmaxf(acc + fc1b[kk], 0.f);
        partv = hk * fc2W[kk];
    }
    r2[t] = partv; __syncthreads();
    for (int s = 128; s > 0; s >>= 1) { if (t < s) r2[t] += r2[t + s]; __syncthreads(); }
    if (t == 0) atomicAdd(&out[b], r2[0]);
}

extern "C" void kernel_launch(void* const* d_in, const int* in_sizes, int n_in,
                              void* d_out, int out_size, void* d_ws, size_t ws_size,
                              hipStream_t stream) {
    const int*   topic_ids = (const int*)d_in[0];
    const int*   adj       = (const int*)d_in[1];
    const float* tm        = (const float*)d_in[2];
    const float* attr      = (const float*)d_in[3];
    const float* emb       = (const float*)d_in[4];
    const float* sW        = (const float*)d_in[5];
    const float* sb        = (const float*)d_in[6];
    const float* aW        = (const float*)d_in[7];
    const float* ab        = (const float*)d_in[8];
    const float* gW        = (const float*)d_in[9];   // (2,8,512,64)
    const float* ga        = (const float*)d_in[10];  // (2,8,128,1)
    const float* fc1W      = (const float*)d_in[11];
    const float* fc1b      = (const float*)d_in[12];
    const float* fc2W      = (const float*)d_in[13];
    const float* fc2b      = (const float*)d_in[14];
    float* out = (float*)d_out;

    char* p = (char*)d_ws;
    us* TWb    = (us*)p; p += sizeof(us) * (size_t)NB * NT * NT;        // 16.8 MB
    us* E1     = (us*)p; p += sizeof(us) * (size_t)NH * NT * NT;        // 16.8 MB
    us* node0b = (us*)p; p += sizeof(us) * (size_t)NT * HID;            // 1 MB
    us* Wt     = (us*)p; p += sizeof(us) * (size_t)2 * NH * HD * HID;   // 1 MB
    us* Ht1    = (us*)p; p += sizeof(us) * (size_t)HID * NT;            // 1 MB
    us* node1b = (us*)p; p += sizeof(us) * (size_t)NB * NT * HID;       // 8 MB
    float* es1  = (float*)p; p += sizeof(float) * NH * NT;
    float* ed1  = (float*)p; p += sizeof(float) * NH * NT;
    // zero region (contiguous): es2q, pv, pl
    float* es2q = (float*)p; p += sizeof(float) * NB * NH;              // 256 B
    float* pv   = (float*)p; p += sizeof(float) * NB * NH * HD;         // 16 KB
    float* pl   = (float*)p; p += sizeof(float) * NB * NH;              // 256 B
    float* ws2  = (float*)p; p += sizeof(float) * 16 * HID;             // 32 KB
    float* part = (float*)p; p += sizeof(float) * 1024;

    kprep<<<1288, 256, 0, stream>>>(tm, part, emb, sW, sb, node0b, gW, Wt, ga, ws2, fc2b, out);
    kphase1<<<2181, 256, 0, stream>>>(tm, adj, part, TWb, node0b, Wt, ga, Ht1, es1, ed1, es2q);
    kedge<<<2048, 256, 0, stream>>>(es1, ed1, E1);
    kattn1<<<dim3(16 * NB, NH), 256, 0, stream>>>(TWb, Ht1, E1, ws2, topic_ids, node1b, es2q);
    kgemm2<<<dim3(16 * NB, NH), 256, 0, stream>>>(node1b, Wt + (size_t)NH * HD * HID, TWb,
                                                  ga + NH * 2 * HD, es2q, topic_ids, pv, pl);
    khead2<<<dim3(32, NB), 256, 0, stream>>>(pv, pl, attr, aW, ab, fc1W, fc1b, fc2W, out);
}